// Round 16
// baseline (28.053 us; speedup 1.0000x reference)
//
#include <hip/hip_runtime.h>

// Cost volume loss: pred/target (8,3,512,512) f32.
// Per pixel: min over 5x5 offsets (zero-padded target) of mean_C |pred - patch|,
// then global mean. Output: single f32 scalar.
//
// r16 = r11's proven main (4 cols x 4 rows/thread, 3.75 loads/px, 8 waves/CU,
// branch-free clamped-row loop) + single-dispatch epilogue via threadfence
// last-block reduction. Counter needs NO init: "last" = (old mod 512 == 511),
// valid for any initial value since 512 | 2^32 (poison/replay safe).
// Ledger: loads/px drives runtime (r1 78/px=112us, r3 5.25=22, r11 3.75=19);
// below 3.75 all regressed (r12 tall-tile, r13 LDS, r14 shuffle); tiny
// hipMemsetAsync = ~8us in-graph fill dispatch (r15) -> avoid.

#define H_DIM 512
#define W_DIM 512
#define N_DIM 8
#define C_DIM 3
#define HW (H_DIM * W_DIM)
#define CHW (C_DIM * HW)
#define NPIX (N_DIM * HW)
#define NBLOCKS 512
#define BIGF 3.0e38f

typedef float f4 __attribute__((ext_vector_type(4)));

__global__ __launch_bounds__(256, 2) void cvl_main(const float* __restrict__ pred,
                                                   const float* __restrict__ targ,
                                                   float* __restrict__ partial,
                                                   unsigned* __restrict__ counter,
                                                   float* __restrict__ out) {
    const int tid = threadIdx.x;
    const int col = tid & 127;        // 0..127
    const int rg  = tid >> 7;         // 0..1 (wave-uniform)
    const int bid = blockIdx.x;       // 0..511
    const int n   = bid >> 6;         // 0..7
    const int hg  = bid & 63;         // 0..63
    const int h0  = hg * 8 + rg * 4;  // first of this thread's 4 rows (wave-uniform)
    const int w0  = col * 4;          // first of this thread's 4 cols

    const size_t nbase = (size_t)n * CHW;

    // ---- pred: 4 rows x 3 channels x 4 px, nontemporal (streamed once) ----
    f4 pv[4][3];
#pragma unroll
    for (int r = 0; r < 4; ++r)
#pragma unroll
        for (int c = 0; c < 3; ++c)
            pv[r][c] = __builtin_nontemporal_load(
                (const f4*)(pred + nbase + (size_t)c * HW +
                            (size_t)(h0 + r) * W_DIM + w0));

    const bool wlo = (col == 0);          // w0 == 0
    const bool whi = (col == 127);        // w0 == 508
    const int am = wlo ? 0 : (w0 - 2);            // left window load col
    const int bp = whi ? (W_DIM - 4) : (w0 + 2);  // right window load col
    const float* trow = targ + nbase;

    // ---- seed best: border pixels get the zero-pad candidate sum|pred| ----
    float best[4][4];
#pragma unroll
    for (int r = 0; r < 4; ++r) {
        const int hp = h0 + r;
        const bool hcand = (hp < 2) || (hp >= H_DIM - 2);
#pragma unroll
        for (int px = 0; px < 4; ++px) {
            const bool wcand = (px < 2) ? wlo : whi;
            const float soob =
                fabsf(pv[r][0][px]) + fabsf(pv[r][1][px]) + fabsf(pv[r][2][px]);
            best[r][px] = (hcand || wcand) ? soob : BIGF;
        }
    }

    // ---- 8 target rows, branch-free (clamped addresses) ----
#pragma unroll
    for (int j = 0; j < 8; ++j) {
        const int hh = h0 - 2 + j;                       // wave-uniform
        const bool rowok = (hh >= 0) && (hh < H_DIM);    // wave-uniform
        const int hc = (hh < 0) ? 0 : ((hh >= H_DIM) ? (H_DIM - 1) : hh);

        // 8-float window per channel: cols [w0-2, w0+6), unconditional loads
        float w[3][8];
#pragma unroll
        for (int c = 0; c < 3; ++c) {
            const float* rowp = trow + (size_t)c * HW + (size_t)hc * W_DIM;
            const f4 a = *(const f4*)(rowp + am);
            const f4 b = *(const f4*)(rowp + bp);
            w[c][0] = a[0];
            w[c][1] = a[1];
            w[c][2] = wlo ? a[0] : a[2];   // col 0 at left edge
            w[c][3] = wlo ? a[1] : a[3];   // col 1 at left edge
            w[c][4] = whi ? b[2] : b[0];   // col 510 at right edge
            w[c][5] = whi ? b[3] : b[1];   // col 511 at right edge
            w[c][6] = b[2];
            w[c][7] = b[3];
        }

#pragma unroll
        for (int r = 0; r < 4; ++r) {
            const int di = j - 2 - r;          // compile-time after unroll
            if (di >= -2 && di <= 2) {
#pragma unroll
                for (int px = 0; px < 4; ++px) {
                    float rm = BIGF;           // min over dj for this row
#pragma unroll
                    for (int dj = -2; dj <= 2; ++dj) {
                        const int ix = px + dj + 2;  // 0..7
                        float s = fabsf(pv[r][0][px] - w[0][ix])
                                + fabsf(pv[r][1][px] - w[1][ix])
                                + fabsf(pv[r][2][px] - w[2][ix]);
                        // out-of-image candidates invalid at w edges:
                        if (px + dj < 0)      s = wlo ? BIGF : s;
                        else if (px + dj > 3) s = whi ? BIGF : s;
                        rm = fminf(rm, s);
                    }
                    // suppress clamped (out-of-image) rows — wave-uniform:
                    best[r][px] = fminf(best[r][px], rowok ? rm : BIGF);
                }
            }
        }
    }

    // ---- block reduce: 16 px -> thread, wave shuffle, LDS, one store ----
    float v = 0.0f;
#pragma unroll
    for (int r = 0; r < 4; ++r)
#pragma unroll
        for (int px = 0; px < 4; ++px)
            v += best[r][px];

#pragma unroll
    for (int o = 32; o > 0; o >>= 1) v += __shfl_down(v, o, 64);

    __shared__ float ws[4];
    __shared__ int lastflag;
    const int lane = tid & 63;
    const int wv   = tid >> 6;
    if (lane == 0) ws[wv] = v;
    __syncthreads();
    if (tid == 0) {
        partial[bid] = ws[0] + ws[1] + ws[2] + ws[3];
        __threadfence();                          // publish partial device-wide
        const unsigned old = atomicAdd(counter, 1u);
        // last block of this dispatch, valid for ANY counter start value:
        lastflag = ((old & (NBLOCKS - 1)) == (NBLOCKS - 1));
    }
    __syncthreads();

    // ---- last block reduces all 512 partials -> out[0] ----
    if (lastflag) {
        __threadfence();                          // acquire: see all partials
        volatile const float* vp = partial;
        double dv = (double)vp[tid] + (double)vp[tid + 256];
#pragma unroll
        for (int o = 32; o > 0; o >>= 1) dv += __shfl_down(dv, o, 64);

        __shared__ double wd[4];
        if (lane == 0) wd[wv] = dv;
        __syncthreads();
        if (tid == 0) {
            const double s = wd[0] + wd[1] + wd[2] + wd[3];
            out[0] = (float)(s / (3.0 * (double)NPIX));
        }
    }
}

extern "C" void kernel_launch(void* const* d_in, const int* in_sizes, int n_in,
                              void* d_out, int out_size, void* d_ws, size_t ws_size,
                              hipStream_t stream) {
    const float* pred = (const float*)d_in[0];
    const float* targ = (const float*)d_in[1];
    float* out = (float*)d_out;
    float* partial = (float*)d_ws;
    unsigned* counter = (unsigned*)((char*)d_ws + NBLOCKS * sizeof(float));

    cvl_main<<<NBLOCKS, 256, 0, stream>>>(pred, targ, partial, counter, out);
}

// Round 17
// 19.294 us; speedup vs baseline: 1.4540x; 1.4540x over previous
//
#include <hip/hip_runtime.h>

// Cost volume loss: pred/target (8,3,512,512) f32.
// Per pixel: min over 5x5 offsets (zero-padded target) of mean_C |pred - patch|,
// then global mean. Output: single f32 scalar.
//
// r17 = r11 verbatim (measured optimum, 19.1us). Ledger:
//   loads/px drives runtime at >=2 waves/SIMD: r1 78/px=112us, r3 5.25=22.4,
//   r11 3.75=19.1. Below 3.75 requires bigger tiles -> fewer waves -> loses
//   (r12 3.0/px @1 wave/SIMD = 23.1). More TLP requires smaller tiles -> more
//   loads -> loses (r8 5.25 @4 waves = 23.4). LDS staging (r4,r13), shuffle
//   halo (r14), sw pipeline (r7), branch-free specialization (r9 spilled)
//   all regressed. Single-dispatch epilogues all poisoned: 4B memsetAsync =
//   ~8us fill dispatch (r15); threadfence protocol = invalidate storm + the
//   mod-512 last-block trick is init-dependent (r16, absmax 2e-3); coop
//   grid.sync = ~40us (r6). Two-dispatch + 512-float final kernel stands.

#define H_DIM 512
#define W_DIM 512
#define N_DIM 8
#define C_DIM 3
#define HW (H_DIM * W_DIM)
#define CHW (C_DIM * HW)
#define NPIX (N_DIM * HW)
#define NBLOCKS 512
#define BIGF 3.0e38f

typedef float f4 __attribute__((ext_vector_type(4)));

__global__ __launch_bounds__(256, 2) void cvl_main(const float* __restrict__ pred,
                                                   const float* __restrict__ targ,
                                                   float* __restrict__ partial) {
    const int tid = threadIdx.x;
    const int col = tid & 127;        // 0..127
    const int rg  = tid >> 7;         // 0..1 (wave-uniform)
    const int bid = blockIdx.x;       // 0..511
    const int n   = bid >> 6;         // 0..7
    const int hg  = bid & 63;         // 0..63
    const int h0  = hg * 8 + rg * 4;  // first of this thread's 4 rows (wave-uniform)
    const int w0  = col * 4;          // first of this thread's 4 cols

    const size_t nbase = (size_t)n * CHW;

    // ---- pred: 4 rows x 3 channels x 4 px, nontemporal (streamed once) ----
    f4 pv[4][3];
#pragma unroll
    for (int r = 0; r < 4; ++r)
#pragma unroll
        for (int c = 0; c < 3; ++c)
            pv[r][c] = __builtin_nontemporal_load(
                (const f4*)(pred + nbase + (size_t)c * HW +
                            (size_t)(h0 + r) * W_DIM + w0));

    const bool wlo = (col == 0);          // w0 == 0
    const bool whi = (col == 127);        // w0 == 508
    const int am = wlo ? 0 : (w0 - 2);            // left window load col
    const int bp = whi ? (W_DIM - 4) : (w0 + 2);  // right window load col
    const float* trow = targ + nbase;

    // ---- seed best: border pixels get the zero-pad candidate sum|pred| ----
    float best[4][4];
#pragma unroll
    for (int r = 0; r < 4; ++r) {
        const int hp = h0 + r;
        const bool hcand = (hp < 2) || (hp >= H_DIM - 2);
#pragma unroll
        for (int px = 0; px < 4; ++px) {
            const bool wcand = (px < 2) ? wlo : whi;
            const float soob =
                fabsf(pv[r][0][px]) + fabsf(pv[r][1][px]) + fabsf(pv[r][2][px]);
            best[r][px] = (hcand || wcand) ? soob : BIGF;
        }
    }

    // ---- 8 target rows, branch-free (clamped addresses) ----
#pragma unroll
    for (int j = 0; j < 8; ++j) {
        const int hh = h0 - 2 + j;                       // wave-uniform
        const bool rowok = (hh >= 0) && (hh < H_DIM);    // wave-uniform
        const int hc = (hh < 0) ? 0 : ((hh >= H_DIM) ? (H_DIM - 1) : hh);

        // 8-float window per channel: cols [w0-2, w0+6), unconditional loads
        float w[3][8];
#pragma unroll
        for (int c = 0; c < 3; ++c) {
            const float* rowp = trow + (size_t)c * HW + (size_t)hc * W_DIM;
            const f4 a = *(const f4*)(rowp + am);
            const f4 b = *(const f4*)(rowp + bp);
            w[c][0] = a[0];
            w[c][1] = a[1];
            w[c][2] = wlo ? a[0] : a[2];   // col 0 at left edge
            w[c][3] = wlo ? a[1] : a[3];   // col 1 at left edge
            w[c][4] = whi ? b[2] : b[0];   // col 510 at right edge
            w[c][5] = whi ? b[3] : b[1];   // col 511 at right edge
            w[c][6] = b[2];
            w[c][7] = b[3];
        }

#pragma unroll
        for (int r = 0; r < 4; ++r) {
            const int di = j - 2 - r;          // compile-time after unroll
            if (di >= -2 && di <= 2) {
#pragma unroll
                for (int px = 0; px < 4; ++px) {
                    float rm = BIGF;           // min over dj for this row
#pragma unroll
                    for (int dj = -2; dj <= 2; ++dj) {
                        const int ix = px + dj + 2;  // 0..7
                        float s = fabsf(pv[r][0][px] - w[0][ix])
                                + fabsf(pv[r][1][px] - w[1][ix])
                                + fabsf(pv[r][2][px] - w[2][ix]);
                        // out-of-image candidates invalid at w edges:
                        if (px + dj < 0)      s = wlo ? BIGF : s;
                        else if (px + dj > 3) s = whi ? BIGF : s;
                        rm = fminf(rm, s);
                    }
                    // suppress clamped (out-of-image) rows — wave-uniform:
                    best[r][px] = fminf(best[r][px], rowok ? rm : BIGF);
                }
            }
        }
    }

    // ---- block reduce: 16 px -> thread, wave shuffle, LDS, one store ----
    float v = 0.0f;
#pragma unroll
    for (int r = 0; r < 4; ++r)
#pragma unroll
        for (int px = 0; px < 4; ++px)
            v += best[r][px];

#pragma unroll
    for (int o = 32; o > 0; o >>= 1) v += __shfl_down(v, o, 64);

    __shared__ float ws[4];
    const int lane = tid & 63;
    const int wv   = tid >> 6;
    if (lane == 0) ws[wv] = v;
    __syncthreads();
    if (tid == 0) partial[bid] = ws[0] + ws[1] + ws[2] + ws[3];
}

__global__ __launch_bounds__(256) void cvl_final(const float* __restrict__ partial,
                                                 float* __restrict__ out) {
    const int tid = threadIdx.x;
    double v = (double)partial[tid] + (double)partial[tid + 256];
#pragma unroll
    for (int o = 32; o > 0; o >>= 1) v += __shfl_down(v, o, 64);

    __shared__ double ws[4];
    const int lane = tid & 63;
    const int wid  = tid >> 6;
    if (lane == 0) ws[wid] = v;
    __syncthreads();
    if (tid == 0) {
        const double s = ws[0] + ws[1] + ws[2] + ws[3];
        out[0] = (float)(s / (3.0 * (double)NPIX));
    }
}

extern "C" void kernel_launch(void* const* d_in, const int* in_sizes, int n_in,
                              void* d_out, int out_size, void* d_ws, size_t ws_size,
                              hipStream_t stream) {
    const float* pred = (const float*)d_in[0];
    const float* targ = (const float*)d_in[1];
    float* out = (float*)d_out;
    float* partial = (float*)d_ws;

    cvl_main<<<NBLOCKS, 256, 0, stream>>>(pred, targ, partial);
    cvl_final<<<1, 256, 0, stream>>>(partial, out);
}

// Round 18
// 19.115 us; speedup vs baseline: 1.4676x; 1.0094x over previous
//
#include <hip/hip_runtime.h>

// Cost volume loss: pred/target (8,3,512,512) f32.
// Per pixel: min over 5x5 offsets (zero-padded target) of mean_C |pred - patch|,
// then global mean. Output: single f32 scalar.
//
// r18 = r11 main verbatim (measured optimum) + minimized final kernel:
// 1 wave x 64 lanes, 2xf4 loads/lane (128 f4 loads, all in flight), f32 tree
// reduce (32-bit shuffles), single store. Ledger in r17 comment history.

#define H_DIM 512
#define W_DIM 512
#define N_DIM 8
#define C_DIM 3
#define HW (H_DIM * W_DIM)
#define CHW (C_DIM * HW)
#define NPIX (N_DIM * HW)
#define NBLOCKS 512
#define BIGF 3.0e38f

typedef float f4 __attribute__((ext_vector_type(4)));

__global__ __launch_bounds__(256, 2) void cvl_main(const float* __restrict__ pred,
                                                   const float* __restrict__ targ,
                                                   float* __restrict__ partial) {
    const int tid = threadIdx.x;
    const int col = tid & 127;        // 0..127
    const int rg  = tid >> 7;         // 0..1 (wave-uniform)
    const int bid = blockIdx.x;       // 0..511
    const int n   = bid >> 6;         // 0..7
    const int hg  = bid & 63;         // 0..63
    const int h0  = hg * 8 + rg * 4;  // first of this thread's 4 rows (wave-uniform)
    const int w0  = col * 4;          // first of this thread's 4 cols

    const size_t nbase = (size_t)n * CHW;

    // ---- pred: 4 rows x 3 channels x 4 px, nontemporal (streamed once) ----
    f4 pv[4][3];
#pragma unroll
    for (int r = 0; r < 4; ++r)
#pragma unroll
        for (int c = 0; c < 3; ++c)
            pv[r][c] = __builtin_nontemporal_load(
                (const f4*)(pred + nbase + (size_t)c * HW +
                            (size_t)(h0 + r) * W_DIM + w0));

    const bool wlo = (col == 0);          // w0 == 0
    const bool whi = (col == 127);        // w0 == 508
    const int am = wlo ? 0 : (w0 - 2);            // left window load col
    const int bp = whi ? (W_DIM - 4) : (w0 + 2);  // right window load col
    const float* trow = targ + nbase;

    // ---- seed best: border pixels get the zero-pad candidate sum|pred| ----
    float best[4][4];
#pragma unroll
    for (int r = 0; r < 4; ++r) {
        const int hp = h0 + r;
        const bool hcand = (hp < 2) || (hp >= H_DIM - 2);
#pragma unroll
        for (int px = 0; px < 4; ++px) {
            const bool wcand = (px < 2) ? wlo : whi;
            const float soob =
                fabsf(pv[r][0][px]) + fabsf(pv[r][1][px]) + fabsf(pv[r][2][px]);
            best[r][px] = (hcand || wcand) ? soob : BIGF;
        }
    }

    // ---- 8 target rows, branch-free (clamped addresses) ----
#pragma unroll
    for (int j = 0; j < 8; ++j) {
        const int hh = h0 - 2 + j;                       // wave-uniform
        const bool rowok = (hh >= 0) && (hh < H_DIM);    // wave-uniform
        const int hc = (hh < 0) ? 0 : ((hh >= H_DIM) ? (H_DIM - 1) : hh);

        // 8-float window per channel: cols [w0-2, w0+6), unconditional loads
        float w[3][8];
#pragma unroll
        for (int c = 0; c < 3; ++c) {
            const float* rowp = trow + (size_t)c * HW + (size_t)hc * W_DIM;
            const f4 a = *(const f4*)(rowp + am);
            const f4 b = *(const f4*)(rowp + bp);
            w[c][0] = a[0];
            w[c][1] = a[1];
            w[c][2] = wlo ? a[0] : a[2];   // col 0 at left edge
            w[c][3] = wlo ? a[1] : a[3];   // col 1 at left edge
            w[c][4] = whi ? b[2] : b[0];   // col 510 at right edge
            w[c][5] = whi ? b[3] : b[1];   // col 511 at right edge
            w[c][6] = b[2];
            w[c][7] = b[3];
        }

#pragma unroll
        for (int r = 0; r < 4; ++r) {
            const int di = j - 2 - r;          // compile-time after unroll
            if (di >= -2 && di <= 2) {
#pragma unroll
                for (int px = 0; px < 4; ++px) {
                    float rm = BIGF;           // min over dj for this row
#pragma unroll
                    for (int dj = -2; dj <= 2; ++dj) {
                        const int ix = px + dj + 2;  // 0..7
                        float s = fabsf(pv[r][0][px] - w[0][ix])
                                + fabsf(pv[r][1][px] - w[1][ix])
                                + fabsf(pv[r][2][px] - w[2][ix]);
                        // out-of-image candidates invalid at w edges:
                        if (px + dj < 0)      s = wlo ? BIGF : s;
                        else if (px + dj > 3) s = whi ? BIGF : s;
                        rm = fminf(rm, s);
                    }
                    // suppress clamped (out-of-image) rows — wave-uniform:
                    best[r][px] = fminf(best[r][px], rowok ? rm : BIGF);
                }
            }
        }
    }

    // ---- block reduce: 16 px -> thread, wave shuffle, LDS, one store ----
    float v = 0.0f;
#pragma unroll
    for (int r = 0; r < 4; ++r)
#pragma unroll
        for (int px = 0; px < 4; ++px)
            v += best[r][px];

#pragma unroll
    for (int o = 32; o > 0; o >>= 1) v += __shfl_down(v, o, 64);

    __shared__ float ws[4];
    const int lane = tid & 63;
    const int wv   = tid >> 6;
    if (lane == 0) ws[wv] = v;
    __syncthreads();
    if (tid == 0) partial[bid] = ws[0] + ws[1] + ws[2] + ws[3];
}

__global__ __launch_bounds__(64) void cvl_final(const float* __restrict__ partial,
                                                float* __restrict__ out) {
    const int lane = threadIdx.x;     // 0..63, one wave
    // 512 floats = 64 lanes x 2 f4 loads, all in flight at once
    const f4 a = *(const f4*)(partial + lane * 8);
    const f4 b = *(const f4*)(partial + lane * 8 + 4);
    float v = (a[0] + a[1]) + (a[2] + a[3]) + (b[0] + b[1]) + (b[2] + b[3]);
#pragma unroll
    for (int o = 32; o > 0; o >>= 1) v += __shfl_down(v, o, 64);
    if (lane == 0) out[0] = v * (1.0f / (3.0f * (float)NPIX));
}

extern "C" void kernel_launch(void* const* d_in, const int* in_sizes, int n_in,
                              void* d_out, int out_size, void* d_ws, size_t ws_size,
                              hipStream_t stream) {
    const float* pred = (const float*)d_in[0];
    const float* targ = (const float*)d_in[1];
    float* out = (float*)d_out;
    float* partial = (float*)d_ws;

    cvl_main<<<NBLOCKS, 256, 0, stream>>>(pred, targ, partial);
    cvl_final<<<1, 64, 0, stream>>>(partial, out);
}